// Round 16
// baseline (124.686 us; speedup 1.0000x reference)
//
#include <hip/hip_runtime.h>
#include <hip/hip_bf16.h>

using u32 = unsigned int;
using u16 = unsigned short;

typedef __attribute__((ext_vector_type(8))) _Float16 half8;
typedef __attribute__((ext_vector_type(2))) _Float16 half2v;
typedef __attribute__((ext_vector_type(16))) float f32x16;
typedef __attribute__((ext_vector_type(4))) u32 u32x4;

#define IN_K   4096
#define OUT_N  14336
#define NST    16                // 16 stages x 64k = 1024k per k-quarter wave

// ---------------------------------------------------------------------------
// prep: x f32[64][4096] -> xs f16 in MFMA-fragment order.
// xs layout: [512 chunks][64 rows][8 f16]; chunk c covers k = 8c + perm[j],
// perm = {0,4,1,5,2,6,3,7} (matches pair-dequant element order).
__global__ __launch_bounds__(256) void prep_kernel(const float* __restrict__ x,
                                                   u16* __restrict__ xs) {
  const int t = blockIdx.x * 256 + threadIdx.x;   // 32768 threads
  const int c = t >> 6;        // chunk 0..511
  const int r = t & 63;        // row
  const float* px = x + r * IN_K + c * 8;
  const float4 a = *(const float4*)px;
  const float4 b = *(const float4*)(px + 4);
  const float af[4] = {a.x, a.y, a.z, a.w};
  const float bf[4] = {b.x, b.y, b.z, b.w};
  union { u32x4 v; u32 u[4]; } o;
#pragma unroll
  for (int i = 0; i < 4; ++i) {
    const _Float16 hl = (_Float16)af[i];   // k = 8c + i
    const _Float16 hh = (_Float16)bf[i];   // k = 8c + i + 4
    u16 lo, hi;
    __builtin_memcpy(&lo, &hl, 2);
    __builtin_memcpy(&hi, &hh, 2);
    o.u[i] = (u32)lo | ((u32)hi << 16);
  }
  *(u32x4*)(xs + (size_t)t * 8) = o.v;
}

// dequant one qweight word (8 weights, fragment order) -> f16x8 B-fragment
static __device__ __forceinline__ half8 dequant8(u32 q, half2v hz, half2v s2) {
  const u32 p0 = (q & 0x000F000Fu) | 0x64006400u;          // (n0,n4)+1024
  const u32 p1 = ((q >> 4) & 0x000F000Fu) | 0x64006400u;   // (n1,n5)+1024
  const u32 p2 = ((q >> 8) & 0x000F000Fu) | 0x64006400u;   // (n2,n6)+1024
  const u32 p3 = ((q >> 12) & 0x000F000Fu) | 0x64006400u;  // (n3,n7)+1024
  half2v t0, t1, t2, t3;
  __builtin_memcpy(&t0, &p0, 4);
  __builtin_memcpy(&t1, &p1, 4);
  __builtin_memcpy(&t2, &p2, 4);
  __builtin_memcpy(&t3, &p3, 4);
  union { half8 v; half2v h[4]; } bb;
  bb.h[0] = (t0 - hz) * s2;    // exact int sub, then scale (v_pk_*_f16)
  bb.h[1] = (t1 - hz) * s2;
  bb.h[2] = (t2 - hz) * s2;
  bb.h[3] = (t3 - hz) * s2;
  return bb.v;
}

// ---------------------------------------------------------------------------
// Fused qgemm (R15 structure) with IN-KERNEL REP LOOP for measurement:
// the whole body runs REPS times per dispatch (acc reset per rep, identical
// epilogue writes -> idempotent). Makes the dispatch long enough to appear
// in rocprof top-5 AND gives per-rep warm core time = (dur - base)/(REPS-1).
template <int REPS>
__global__ __launch_bounds__(256, 2) void qgemm_kernel(
    const u32* __restrict__ qw, const u32* __restrict__ qz,
    const float* __restrict__ scal, const u16* __restrict__ xs,
    const float* __restrict__ bias, float* __restrict__ out) {
  __shared__ alignas(16) char smem[73728];   // 4 waves x 18 KB
  const int tid = threadIdx.x;               // 0..255
  const int lane = tid & 63;
  const int g = lane >> 5;                   // k-half within 16k step
  const int nn = lane & 31;                  // col within 32-col tile
  const int kq = tid >> 6;                   // wave = k-quarter 0..3
  const int bx = blockIdx.x;
  const int bxp = (bx & 7) * 56 + (bx >> 3); // XCD-contiguous col-block
  const int colabs = bxp * 32 + nn;
  const int zsh = (nn & 7) * 4;
  char* const base = smem + kq * 18432;      // private: A 2x8KB @0, Q 2x1KB @16384

#pragma unroll 1
  for (int rep = 0; rep < REPS; ++rep) {
    f32x16 acc0, acc1;
#pragma unroll
    for (int i = 0; i < 16; ++i) { acc0[i] = 0.f; acc1[i] = 0.f; }

    // scales & zero-words for this quarter's 8 groups -> registers, then drain
    float sv[8]; u32 zv[8];
#pragma unroll
    for (int t = 0; t < 8; ++t) {
      sv[t] = scal[(size_t)(kq * 8 + t) * OUT_N + colabs];
      zv[t] = qz[(size_t)(kq * 8 + t) * (OUT_N / 8) + (colabs >> 3)];
    }
    asm volatile("s_waitcnt vmcnt(0)" ::: "memory");

    // per-wave stage issue: A 8 instr + Q 1 instr = 9 VMEM (all 1 KB wide)
    auto issue = [&](int st) {
      const int slot = st & 1;
      char* ab = base + slot * 8192;
      char* qb = base + 16384 + slot * 1024;
      const u16* asrc = xs + (size_t)(kq * 128 + st * 8) * 512;   // 8 KB linear
#pragma unroll
      for (int r = 0; r < 8; ++r) {
        const int p = r * 64 + lane;           // 16B chunk 0..511
        __builtin_amdgcn_global_load_lds(
            (const __attribute__((address_space(1))) void*)(asrc + p * 8),
            (__attribute__((address_space(3))) void*)(ab + p * 16), 16, 0, 0);
      }
      const int j = lane >> 3, cg = lane & 7;  // Q: 8 rows x 128 B
      const u32* qsrc = qw + (size_t)(kq * 128 + st * 8 + j) * OUT_N
                           + bxp * 32 + cg * 4;
      __builtin_amdgcn_global_load_lds(
          (const __attribute__((address_space(1))) void*)qsrc,
          (__attribute__((address_space(3))) void*)(qb + lane * 16), 16, 0, 0);
    };

    issue(0); issue(1);                        // 18 outstanding (per wave)

#pragma unroll
    for (int st = 0; st < NST; ++st) {
      if (st < NST - 1)
        asm volatile("s_waitcnt vmcnt(9)" ::: "memory");  // own stage st done
      else
        asm volatile("s_waitcnt vmcnt(0)" ::: "memory");

      const int gi = st >> 1;                  // group = 128 k = 2 stages
      const u32 zq = (zv[gi] >> zsh) & 0xFu;
      const u32 hzu = 0x64016401u + zq * 0x00010001u;     // f16x2 of (1025+z)
      half2v hz; __builtin_memcpy(&hz, &hzu, 4);
      const _Float16 hs = (_Float16)sv[gi];
      const half2v s2 = {hs, hs};

      const u16* ab = (const u16*)(base + (st & 1) * 8192);
      const u32* qb = (const u32*)(base + 16384 + (st & 1) * 1024);
      __builtin_amdgcn_s_setprio(1);
#pragma unroll
      for (int s = 0; s < 4; ++s) {
        const int cl = s * 2 + g;              // 8k-chunk within stage (0..7)
        const half8 a0 = *(const half8*)(ab + (cl * 64 + nn) * 8);
        const half8 a1 = *(const half8*)(ab + (cl * 64 + nn + 32) * 8);
        const u32 q = qb[cl * 32 + nn];
        const half8 bb = dequant8(q, hz, s2);
        acc0 = __builtin_amdgcn_mfma_f32_32x32x16_f16(a0, bb, acc0, 0, 0, 0);
        acc1 = __builtin_amdgcn_mfma_f32_32x32x16_f16(a1, bb, acc1, 0, 0, 0);
      }
      __builtin_amdgcn_s_setprio(0);

      if (st + 2 < NST) {
        asm volatile("s_waitcnt lgkmcnt(0)" ::: "memory"); // WAR on own slot
        issue(st + 2);
      }
    }

    // ---- in-block split-K reduction via LDS (reuses ring space) ----
    __syncthreads();                           // all waves done computing
    float* ep = (float*)smem + kq * 2048;      // [64 rows][32 cols] f32 = 8 KB
#pragma unroll
    for (int r = 0; r < 16; ++r) {
      const int row0 = (r & 3) + 8 * (r >> 2) + 4 * g;
      ep[row0 * 32 + nn] = acc0[r];
      ep[(row0 + 32) * 32 + nn] = acc1[r];
    }
    __syncthreads();
    // 256 threads x 8 f32: sum 4 quarters + bias -> out (order: bias, q0..q3)
    const int pos = tid * 8;                   // 0..2040
    const int row = pos >> 5;
    const int colb = pos & 31;
    const float* eb = (const float*)smem;
    float4 v0 = *(const float4*)(bias + bxp * 32 + colb);
    float4 v1 = *(const float4*)(bias + bxp * 32 + colb + 4);
#pragma unroll
    for (int q = 0; q < 4; ++q) {
      const float4 a = *(const float4*)(eb + q * 2048 + pos);
      const float4 b = *(const float4*)(eb + q * 2048 + pos + 4);
      v0.x += a.x; v0.y += a.y; v0.z += a.z; v0.w += a.w;
      v1.x += b.x; v1.y += b.y; v1.z += b.z; v1.w += b.w;
    }
    float* po = out + (size_t)row * OUT_N + bxp * 32 + colb;
    *(float4*)po = v0;
    *(float4*)(po + 4) = v1;
    __syncthreads();                           // epilogue reads done before next rep's staging
  }
}

// ---------------------------------------------------------------------------
extern "C" void kernel_launch(void* const* d_in, const int* in_sizes, int n_in,
                              void* d_out, int out_size, void* d_ws, size_t ws_size,
                              hipStream_t stream) {
  (void)in_sizes; (void)n_in; (void)out_size; (void)ws_size;
  const float* x    = (const float*)d_in[0];
  const u32*   qw   = (const u32*)d_in[1];
  const u32*   qz   = (const u32*)d_in[2];
  const float* sc   = (const float*)d_in[3];
  const float* bias = (const float*)d_in[4];
  // d_in[5] = g_idx: sequential k/128 for this problem; folded into indexing.
  float* out = (float*)d_out;
  u16* xs = (u16*)d_ws;                      // 512 KB scratch

  prep_kernel<<<128, 256, 0, stream>>>(x, xs);
  qgemm_kernel<4><<<448, 256, 0, stream>>>(qw, qz, sc, xs, bias, out);
}

// Round 17
// 26.430 us; speedup vs baseline: 4.7176x; 4.7176x over previous
//
#include <hip/hip_runtime.h>
#include <hip/hip_bf16.h>

using u32 = unsigned int;
using u16 = unsigned short;

typedef __attribute__((ext_vector_type(8))) _Float16 half8;
typedef __attribute__((ext_vector_type(2))) _Float16 half2v;
typedef __attribute__((ext_vector_type(16))) float f32x16;
typedef __attribute__((ext_vector_type(4))) u32 u32x4;

#define IN_K   4096
#define OUT_N  14336
#define NST    32                // 32 stages x 32k = 1024k per k-quarter wave

// ---------------------------------------------------------------------------
// prep: x f32[64][4096] -> xs f16 in MFMA-fragment order.
// xs layout: [512 chunks][64 rows][8 f16]; chunk c covers k = 8c + perm[j],
// perm = {0,4,1,5,2,6,3,7} (matches pair-dequant element order).
__global__ __launch_bounds__(256) void prep_kernel(const float* __restrict__ x,
                                                   u16* __restrict__ xs) {
  const int t = blockIdx.x * 256 + threadIdx.x;   // 32768 threads
  const int c = t >> 6;        // chunk 0..511
  const int r = t & 63;        // row
  const float* px = x + r * IN_K + c * 8;
  const float4 a = *(const float4*)px;
  const float4 b = *(const float4*)(px + 4);
  const float af[4] = {a.x, a.y, a.z, a.w};
  const float bf[4] = {b.x, b.y, b.z, b.w};
  union { u32x4 v; u32 u[4]; } o;
#pragma unroll
  for (int i = 0; i < 4; ++i) {
    const _Float16 hl = (_Float16)af[i];   // k = 8c + i
    const _Float16 hh = (_Float16)bf[i];   // k = 8c + i + 4
    u16 lo, hi;
    __builtin_memcpy(&lo, &hl, 2);
    __builtin_memcpy(&hi, &hh, 2);
    o.u[i] = (u32)lo | ((u32)hi << 16);
  }
  *(u32x4*)(xs + (size_t)t * 8) = o.v;
}

// dequant one qweight word (8 weights, fragment order) -> f16x8 B-fragment
static __device__ __forceinline__ half8 dequant8(u32 q, half2v hz, half2v s2) {
  const u32 p0 = (q & 0x000F000Fu) | 0x64006400u;          // (n0,n4)+1024
  const u32 p1 = ((q >> 4) & 0x000F000Fu) | 0x64006400u;   // (n1,n5)+1024
  const u32 p2 = ((q >> 8) & 0x000F000Fu) | 0x64006400u;   // (n2,n6)+1024
  const u32 p3 = ((q >> 12) & 0x000F000Fu) | 0x64006400u;  // (n3,n7)+1024
  half2v t0, t1, t2, t3;
  __builtin_memcpy(&t0, &p0, 4);
  __builtin_memcpy(&t1, &p1, 4);
  __builtin_memcpy(&t2, &p2, 4);
  __builtin_memcpy(&t3, &p3, 4);
  union { half8 v; half2v h[4]; } bb;
  bb.h[0] = (t0 - hz) * s2;    // exact int sub, then scale (v_pk_*_f16)
  bb.h[1] = (t1 - hz) * s2;
  bb.h[2] = (t2 - hz) * s2;
  bb.h[3] = (t3 - hz) * s2;
  return bb.v;
}

// ---------------------------------------------------------------------------
// Fused qgemm: grid 448 x 256 thr, 4 private k-quarter waves, no K-loop
// barriers. SHALLOW-A / DEEP-Q rings: stage = 32 k; A ring-3 (4 x w16 = 4 KB,
// L2-hit stream needs little cover) + Q ring-8 (2 x w4 = 512 B of HBM-miss
// stream -> 7 stages ~3.5 KB pure misses in flight per wave, ~64% of
// outstanding VMEM slots vs 11% in R16). Exact per-stage vmcnt literals
// derived from in-order retirement. LDS 64 KB -> 2 blocks/CU (8 waves/CU).
__global__ __launch_bounds__(256, 2) void qgemm_kernel(
    const u32* __restrict__ qw, const u32* __restrict__ qz,
    const float* __restrict__ scal, const u16* __restrict__ xs,
    const float* __restrict__ bias, float* __restrict__ out) {
  __shared__ alignas(16) char smem[65536];   // 4 waves x 16 KB
  const int tid = threadIdx.x;               // 0..255
  const int lane = tid & 63;
  const int g = lane >> 5;                   // k-half within 16k MFMA step
  const int nn = lane & 31;                  // col within 32-col tile
  const int kq = tid >> 6;                   // wave = k-quarter 0..3
  const int bx = blockIdx.x;
  const int bxp = (bx & 7) * 56 + (bx >> 3); // XCD-contiguous col-block
  const int colabs = bxp * 32 + nn;
  const int zsh = (nn & 7) * 4;
  char* const base = smem + kq * 16384;      // private: A 3x4KB @0, Q 8x512B @12288

  f32x16 acc0, acc1;
#pragma unroll
  for (int i = 0; i < 16; ++i) { acc0[i] = 0.f; acc1[i] = 0.f; }

  // scales & zero-words for this quarter's 8 groups -> registers, then drain
  // so the counted vmcnt region contains ONLY staging loads.
  float sv[8]; u32 zv[8];
#pragma unroll
  for (int t = 0; t < 8; ++t) {
    sv[t] = scal[(size_t)(kq * 8 + t) * OUT_N + colabs];
    zv[t] = qz[(size_t)(kq * 8 + t) * (OUT_N / 8) + (colabs >> 3)];
  }
  asm volatile("s_waitcnt vmcnt(0)" ::: "memory");

  // A stage: 4 KB (4 chunks of 8k), 4 x w16 instrs
  auto issueA = [&](int st) {
    char* ab = base + (st % 3) * 4096;
    const u16* asrc = xs + (size_t)(kq * 128 + st * 4) * 512;
#pragma unroll
    for (int r = 0; r < 4; ++r) {
      const int p = r * 64 + lane;
      __builtin_amdgcn_global_load_lds(
          (const __attribute__((address_space(1))) void*)(asrc + p * 8),
          (__attribute__((address_space(3))) void*)(ab + p * 16), 16, 0, 0);
    }
  };
  // Q stage: 512 B (4 qw rows x 128 B), 2 x w4 instrs (per-lane dword)
  auto issueQ = [&](int st) {
    char* qb = base + 12288 + (st & 7) * 512;
#pragma unroll
    for (int r = 0; r < 2; ++r) {
      const int row = kq * 128 + st * 4 + 2 * r + (lane >> 5);
      const u32* src = qw + (size_t)row * OUT_N + bxp * 32 + (lane & 31);
      __builtin_amdgcn_global_load_lds(
          (const __attribute__((address_space(1))) void*)src,
          (__attribute__((address_space(3))) void*)(qb + r * 256 + lane * 4),
          4, 0, 0);
    }
  };

  // prologue: A 3 deep, Q 8 deep
  issueA(0); issueA(1); issueA(2);
#pragma unroll
  for (int i = 0; i < 8; ++i) issueQ(i);

#pragma unroll
  for (int st = 0; st < NST; ++st) {
    // wait for A(st)+Q(st); literals account for exact issue order/tails
    if (st == 0)       asm volatile("s_waitcnt vmcnt(14)" ::: "memory");
    else if (st == 1)  asm volatile("s_waitcnt vmcnt(18)" ::: "memory");
    else if (st == 2)  asm volatile("s_waitcnt vmcnt(22)" ::: "memory");
    else if (st <= 24) asm volatile("s_waitcnt vmcnt(14)" ::: "memory");
    else if (st == 25) asm volatile("s_waitcnt vmcnt(12)" ::: "memory");
    else if (st == 26) asm volatile("s_waitcnt vmcnt(10)" ::: "memory");
    else if (st <= 29) asm volatile("s_waitcnt vmcnt(8)" ::: "memory");
    else if (st == 30) asm volatile("s_waitcnt vmcnt(4)" ::: "memory");
    else               asm volatile("s_waitcnt vmcnt(0)" ::: "memory");

    const int gi = st >> 2;                  // group = 128 k = 4 stages
    const u32 zq = (zv[gi] >> zsh) & 0xFu;
    const u32 hzu = 0x64016401u + zq * 0x00010001u;     // f16x2 of (1025+z)
    half2v hz; __builtin_memcpy(&hz, &hzu, 4);
    const _Float16 hs = (_Float16)sv[gi];
    const half2v s2 = {hs, hs};

    const char* ab = base + (st % 3) * 4096;
    const char* qb = base + 12288 + (st & 7) * 512;
    __builtin_amdgcn_s_setprio(1);
#pragma unroll
    for (int s = 0; s < 2; ++s) {
      const int cl = s * 2 + g;              // 8k-chunk within stage (0..3)
      const half8 a0 = *(const half8*)(ab + (cl * 64 + nn) * 16);
      const half8 a1 = *(const half8*)(ab + (cl * 64 + nn + 32) * 16);
      const u32 q = *(const u32*)(qb + (cl * 32 + nn) * 4);
      const half8 bb = dequant8(q, hz, s2);
      acc0 = __builtin_amdgcn_mfma_f32_32x32x16_f16(a0, bb, acc0, 0, 0, 0);
      acc1 = __builtin_amdgcn_mfma_f32_32x32x16_f16(a1, bb, acc1, 0, 0, 0);
    }
    __builtin_amdgcn_s_setprio(0);

    // WAR on own ring slots: this wave's ds_reads must have executed
    asm volatile("s_waitcnt lgkmcnt(0)" ::: "memory");
    if (st + 3 < NST) issueA(st + 3);
    if (st + 8 < NST) issueQ(st + 8);
  }

  // ---- in-block split-K reduction via LDS (reuses ring space) ----
  __syncthreads();                           // all waves done computing
  float* ep = (float*)smem + kq * 2048;      // [64 rows][32 cols] f32 = 8 KB
#pragma unroll
  for (int r = 0; r < 16; ++r) {
    const int row0 = (r & 3) + 8 * (r >> 2) + 4 * g;
    ep[row0 * 32 + nn] = acc0[r];
    ep[(row0 + 32) * 32 + nn] = acc1[r];
  }
  __syncthreads();
  // 256 threads x 8 f32: sum 4 quarters + bias -> out (order: bias, q0..q3)
  const int pos = tid * 8;                   // 0..2040
  const int row = pos >> 5;
  const int colb = pos & 31;
  const float* eb = (const float*)smem;
  float4 v0 = *(const float4*)(bias + bxp * 32 + colb);
  float4 v1 = *(const float4*)(bias + bxp * 32 + colb + 4);
#pragma unroll
  for (int q = 0; q < 4; ++q) {
    const float4 a = *(const float4*)(eb + q * 2048 + pos);
    const float4 b = *(const float4*)(eb + q * 2048 + pos + 4);
    v0.x += a.x; v0.y += a.y; v0.z += a.z; v0.w += a.w;
    v1.x += b.x; v1.y += b.y; v1.z += b.z; v1.w += b.w;
  }
  float* po = out + (size_t)row * OUT_N + bxp * 32 + colb;
  *(float4*)po = v0;
  *(float4*)(po + 4) = v1;
}

// ---------------------------------------------------------------------------
extern "C" void kernel_launch(void* const* d_in, const int* in_sizes, int n_in,
                              void* d_out, int out_size, void* d_ws, size_t ws_size,
                              hipStream_t stream) {
  (void)in_sizes; (void)n_in; (void)out_size; (void)ws_size;
  const float* x    = (const float*)d_in[0];
  const u32*   qw   = (const u32*)d_in[1];
  const u32*   qz   = (const u32*)d_in[2];
  const float* sc   = (const float*)d_in[3];
  const float* bias = (const float*)d_in[4];
  // d_in[5] = g_idx: sequential k/128 for this problem; folded into indexing.
  float* out = (float*)d_out;
  u16* xs = (u16*)d_ws;                      // 512 KB scratch

  prep_kernel<<<128, 256, 0, stream>>>(x, xs);
  qgemm_kernel<<<448, 256, 0, stream>>>(qw, qz, sc, xs, bias, out);
}